// Round 2
// baseline (682.136 us; speedup 1.0000x reference)
//
#include <hip/hip_runtime.h>
#include <math.h>

#define NB 64      // batch
#define NM 512     // m
#define NS 32768   // NB*NM samples
#define PI_F 3.14159265358979323846f

// ---------------------------------------------------------------------------
// Kernel 1: pooling. inputs [b=64, r=64, c=64, m=512] fp32.
// pooled[q][b*512+j] = sum over the 32x32 quadrant (q = r1*2 + c1).
// ws layout: 4 planes of NS floats.
// Grid: 1024 blocks = b(64) x r1(2) x u(8); 128 threads, thread t owns
// m-values 4t..4t+3 via float4 (coalesced: m is the contiguous axis).
// ---------------------------------------------------------------------------
__global__ __launch_bounds__(128) void pool_kernel(const float* __restrict__ in,
                                                   float* __restrict__ ws) {
    const int bid = blockIdx.x;       // 0..1023
    const int b   = bid >> 4;         // 0..63
    const int r1  = (bid >> 3) & 1;   // 0..1
    const int u   = bid & 7;          // 0..7 -> 4 rows each
    const int t   = threadIdx.x;      // 0..127

    const float4* in4 = (const float4*)in;
    float4 lo = make_float4(0.f, 0.f, 0.f, 0.f);
    float4 hi = make_float4(0.f, 0.f, 0.f, 0.f);

    const int rbase = r1 * 32 + u * 4;
    for (int rr = 0; rr < 4; ++rr) {
        const int r = rbase + rr;
        const int rowbase = (b * 64 + r) * 64;  // in units of c
        #pragma unroll 4
        for (int c = 0; c < 32; ++c) {
            float4 v = in4[(rowbase + c) * 128 + t];
            lo.x += v.x; lo.y += v.y; lo.z += v.z; lo.w += v.w;
        }
        #pragma unroll 4
        for (int c = 32; c < 64; ++c) {
            float4 v = in4[(rowbase + c) * 128 + t];
            hi.x += v.x; hi.y += v.y; hi.z += v.z; hi.w += v.w;
        }
    }

    const int off = b * NM + 4 * t;
    float* pl = ws + (r1 * 2 + 0) * NS + off;
    float* ph = ws + (r1 * 2 + 1) * NS + off;
    atomicAdd(pl + 0, lo.x); atomicAdd(pl + 1, lo.y);
    atomicAdd(pl + 2, lo.z); atomicAdd(pl + 3, lo.w);
    atomicAdd(ph + 0, hi.x); atomicAdd(ph + 1, hi.y);
    atomicAdd(ph + 2, hi.z); atomicAdd(ph + 3, hi.w);
}

// ---------------------------------------------------------------------------
// Kernel 2: 4-qubit statevector sim, one thread per (b, j) sample.
// State = 16 complex amps in registers; all indices compile-time (no scratch).
// Qubit q maps to bit (3-q) of the basis index (wire 0 = MSB).
// ---------------------------------------------------------------------------
template<int BIT>
__device__ __forceinline__ void apply_ry(float* re, float* im, float c, float s) {
    #pragma unroll
    for (int i = 0; i < 16; ++i) {
        if (!(i & BIT)) {
            const int i1 = i | BIT;
            float r0 = re[i], m0 = im[i], r1 = re[i1], m1 = im[i1];
            re[i]  = c * r0 - s * r1;  im[i]  = c * m0 - s * m1;
            re[i1] = s * r0 + c * r1;  im[i1] = s * m0 + c * m1;
        }
    }
}

template<int BIT>
__device__ __forceinline__ void apply_rot(float* re, float* im,
                                          float ar, float ai, float br, float bi,
                                          float cr, float ci, float dr, float di) {
    #pragma unroll
    for (int i = 0; i < 16; ++i) {
        if (!(i & BIT)) {
            const int i1 = i | BIT;
            float r0 = re[i], m0 = im[i], r1 = re[i1], m1 = im[i1];
            re[i]  = ar * r0 - ai * m0 + br * r1 - bi * m1;
            im[i]  = ar * m0 + ai * r0 + br * m1 + bi * r1;
            re[i1] = cr * r0 - ci * m0 + dr * r1 - di * m1;
            im[i1] = cr * m0 + ci * r0 + dr * m1 + di * r1;
        }
    }
}

template<int CM, int TM>
__device__ __forceinline__ void cnot(float* re, float* im) {
    #pragma unroll
    for (int i = 0; i < 16; ++i) {
        if ((i & CM) && !(i & TM)) {
            const int i1 = i | TM;
            float tr = re[i]; re[i] = re[i1]; re[i1] = tr;
            float ti = im[i]; im[i] = im[i1]; im[i1] = ti;
        }
    }
}

__global__ __launch_bounds__(256) void sim_kernel(const float* __restrict__ ws,
                                                  const float* __restrict__ wq,
                                                  float* __restrict__ out) {
    const int k = blockIdx.x * 256 + threadIdx.x;   // = b*512 + j
    if (k >= NS) return;

    float re[16], im[16];
    #pragma unroll
    for (int i = 0; i < 16; ++i) { re[i] = 0.f; im[i] = 0.f; }
    re[0] = 1.f;

    // Encoding: RY(tanh(mean) * PI) per qubit. half-angle = x * PI/2.
    {
        float s, c, x;
        x = tanhf(ws[0 * NS + k] * (1.f / 1024.f));
        sincosf(x * (PI_F * 0.5f), &s, &c); apply_ry<8>(re, im, c, s);
        x = tanhf(ws[1 * NS + k] * (1.f / 1024.f));
        sincosf(x * (PI_F * 0.5f), &s, &c); apply_ry<4>(re, im, c, s);
        x = tanhf(ws[2 * NS + k] * (1.f / 1024.f));
        sincosf(x * (PI_F * 0.5f), &s, &c); apply_ry<2>(re, im, c, s);
        x = tanhf(ws[3 * NS + k] * (1.f / 1024.f));
        sincosf(x * (PI_F * 0.5f), &s, &c); apply_ry<1>(re, im, c, s);
    }

    // widx = (b*512 + j) // 64 = k >> 6  (matches arange(batch*m)//batch)
    const int widx = k >> 6;

    #pragma unroll
    for (int layer = 0; layer < 2; ++layer) {
        const float* w = wq + widx * 24 + layer * 12;

        #define ROTQ(Q, B)                                                     \
        {                                                                      \
            const float phi = w[(Q) * 3 + 0];                                  \
            const float th  = w[(Q) * 3 + 1];                                  \
            const float om  = w[(Q) * 3 + 2];                                  \
            float ct, st, cp, sp, cm, sm;                                      \
            sincosf(th * 0.5f, &st, &ct);                                      \
            sincosf(0.5f * (phi + om), &sp, &cp);                              \
            sincosf(0.5f * (phi - om), &sm, &cm);                              \
            /* a = e^{-i(phi+om)/2} ct; b = -e^{+i(phi-om)/2} st;   */         \
            /* c = e^{-i(phi-om)/2} st; d = e^{+i(phi+om)/2} ct.    */         \
            apply_rot<B>(re, im,                                               \
                         cp * ct, -sp * ct,   -cm * st, -sm * st,              \
                         cm * st, -sm * st,    cp * ct,  sp * ct);             \
        }

        ROTQ(0, 8) ROTQ(1, 4) ROTQ(2, 2) ROTQ(3, 1)
        #undef ROTQ

        cnot<8, 4>(re, im);  // (0,1)
        cnot<8, 2>(re, im);  // (0,2)
        cnot<8, 1>(re, im);  // (0,3)
        cnot<4, 2>(re, im);  // (1,2)
        cnot<4, 1>(re, im);  // (1,3)
        cnot<2, 1>(re, im);  // (2,3)
    }

    float p0 = 0.f, p1 = 0.f;
    #pragma unroll
    for (int i = 0; i < 8; ++i)  p0 += re[i] * re[i] + im[i] * im[i];
    #pragma unroll
    for (int i = 8; i < 16; ++i) p1 += re[i] * re[i] + im[i] * im[i];

    out[k] = p0 - p1;
}

extern "C" void kernel_launch(void* const* d_in, const int* in_sizes, int n_in,
                              void* d_out, int out_size, void* d_ws, size_t ws_size,
                              hipStream_t stream) {
    const float* in = (const float*)d_in[0];   // [64,64,64,512] fp32
    const float* wq = (const float*)d_in[1];   // [512,2,4,3] fp32
    float* out = (float*)d_out;                // [64,512] fp32
    float* ws  = (float*)d_ws;                 // 4*NS floats = 512 KB

    hipMemsetAsync(d_ws, 0, 4 * NS * sizeof(float), stream);
    pool_kernel<<<dim3(1024), dim3(128), 0, stream>>>(in, ws);
    sim_kernel<<<dim3(NS / 256), dim3(256), 0, stream>>>(ws, wq, out);
}